// Round 1
// baseline (383.508 us; speedup 1.0000x reference)
//
#include <hip/hip_runtime.h>
#include <hip/hip_bf16.h>
#include <cstdint>

// ---------------------------------------------------------------------------
// GemResNetBlock: two gauge-equivariant convs + Fourier ReLU + linear residual
// Round-14: zbuild was latency-bound (31% HBM, 42% VALU, 0 MFMA, 38% occ) on a
// 3-deep dependent gather chain (order->ei->x) repeated serially per edge.
//  * edge_pack prepass: CSR-ordered SRC[] + 48B rec {c1,s1,p[10]} (one sincos
//    per edge total, shared by both layers; kills 2 chain levels)
//  * zbuild2: software-pipelined edge loop (src 1 iter ahead, x/rec issued
//    before computing previous edge), zero-record clamp for branch-free tail
//  * 2 threads per (v,c) on alternating edges, combined via __shfl_xor(.,1)
//    (halves serial depth + wave imbalance, doubles resident waves)
#define NV     20000
#define NE     160000
#define IC1    16
#define OC     32
#define DIN    5
#define NSLOT  49
#define NOUT   160              // (o,i) = 32*5
// ---------------------------------------------------------------------------
struct SlotTables {
    int n;
    int b[64], f[64], i[64], j[64];
    float v[64];
};

constexpr SlotTables make_slots() {
    SlotTables T{};
    float K[19][5][5][5] = {};   // [basis][freq][row i][col j]
    int nb = 0;
    const int BL = 2;
    auto add = [&](int f, const float (*cb)[2], const float (*sb)[2],
                   int m, int n) {
        if (f > BL) return;
        int r0 = (m == 0) ? 0 : (2 * m - 1), nr = (m == 0) ? 1 : 2;
        int c0 = (n == 0) ? 0 : (2 * n - 1), nc = (n == 0) ? 1 : 2;
        for (int a = 0; a < nr; a++)
            for (int bb = 0; bb < nc; bb++) {
                if (f == 0) {
                    K[nb][0][r0 + a][c0 + bb] = cb[a][bb];
                } else {
                    K[nb][2 * f - 1][r0 + a][c0 + bb] = cb[a][bb];
                    K[nb][2 * f    ][r0 + a][c0 + bb] = sb[a][bb];
                }
            }
        nb++;
    };
    const float ONE[2][2]  = {{1, 0}, {0, 0}};
    const float I2[2][2]   = {{1, 0}, {0, 1}};
    const float E2[2][2]   = {{0, -1}, {1, 0}};
    const float S2[2][2]   = {{1, 0}, {0, -1}};
    const float ES2[2][2]  = {{0, 1}, {1, 0}};
    const float NS2[2][2]  = {{-1, 0}, {0, 1}};
    const float C10[2][2]  = {{1, 0}, {0, 0}};
    const float C01[2][2]  = {{0, 0}, {1, 0}};
    const float CM10[2][2] = {{-1, 0}, {0, 0}};
    const float R10[2][2]  = {{1, 0}, {0, 0}};
    const float R01[2][2]  = {{0, 1}, {0, 0}};
    const float RM10[2][2] = {{-1, 0}, {0, 0}};

    for (int m = 0; m <= 2; m++)
        for (int n = 0; n <= 2; n++) {
            if (m == 0 && n == 0) {
                add(0, ONE, ONE, 0, 0);
            } else if (n == 0) {
                add(m, C10, C01, m, 0);
                add(m, C01, CM10, m, 0);
            } else if (m == 0) {
                add(n, R10, R01, 0, n);
                add(n, R01, RM10, 0, n);
            } else {
                int d = m - n;
                int f = d >= 0 ? d : -d;
                float sg = d >= 0 ? 1.f : -1.f;
                const float sgE[2][2]  = {{0, -sg}, {sg, 0}};
                const float msgI[2][2] = {{-sg, 0}, {0, -sg}};
                add(f, I2, sgE, m, n);
                add(f, E2, msgI, m, n);
                add(m + n, S2, ES2, m, n);
                add(m + n, ES2, NS2, m, n);
            }
        }
    T.n = 0;
    for (int i = 0; i < 5; i++)
        for (int b = 0; b < nb; b++)
            for (int f = 0; f < 5; f++)
                for (int j = 0; j < 5; j++)
                    if (K[b][f][i][j] != 0.0f) {
                        T.b[T.n] = b; T.f[T.n] = f; T.i[T.n] = i;
                        T.j[T.n] = j; T.v[T.n] = K[b][f][i][j];
                        T.n++;
                    }
    return T;
}

constexpr SlotTables SL = make_slots();
static_assert(SL.n == NSLOT, "expect 49 kernel-basis nonzeros");

__device__ __forceinline__ uint32_t bf16_rne(float f) {
    uint32_t u = __float_as_uint(f);
    u += 0x7fffu + ((u >> 16) & 1u);
    return u >> 16;
}

typedef __attribute__((ext_vector_type(8))) short bf16x8;   // MFMA A/B frag
typedef __attribute__((ext_vector_type(4))) float f32x4;    // MFMA C/D frag

// ---------------- M build: M[k][n], k=(c*50+j*10+q), n=(o*5+i) -------------
template<int C>
__global__ __launch_bounds__(256) void build_M(const float* __restrict__ W,
                                               float* __restrict__ M) {
    int t = blockIdx.x * 256 + threadIdx.x;
    const int K = C * 50;
    if (t >= K * NOUT) return;
    int n = t % NOUT, k = t / NOUT;
    int o = n / 5, i = n % 5;
    int c = k / 50, r50 = k % 50;
    int j = r50 / 10, q = r50 % 10;
    int f = q >> 1, r = q & 1;
    float acc = 0.f;
    #pragma unroll
    for (int s = 0; s < NSLOT; s++) {
        if (SL.j[s] == j && SL.f[s] == f && SL.i[s] == i)
            acc += SL.v[s] * W[(size_t)((SL.b[s] * 2 + r) * 32 + o) * C + c];
    }
    M[(size_t)k * NOUT + n] = acc;
}

// Swizzle M into MFMA B-fragment order (bf16):
// Mf[((ck*10+nt)*64+lane)*4+a] packs B[k0][col],B[k0+1][col]
// with k0 = ck*32 + (lane>>4)*8 + 2a, col = nt*16 + (lane&15).
template<int K>
__global__ __launch_bounds__(256) void build_Mfrag(const float* __restrict__ M,
                                                   uint32_t* __restrict__ Mf) {
    int t = blockIdx.x * 256 + threadIdx.x;
    const int total = (K / 32) * 10 * 64 * 4;
    if (t >= total) return;
    int a = t & 3;
    int idx = t >> 2;
    int lane = idx & 63; idx >>= 6;
    int nt = idx % 10;
    int ck = idx / 10;
    int col = nt * 16 + (lane & 15);
    int k0 = ck * 32 + (lane >> 4) * 8 + 2 * a;
    uint32_t lo = bf16_rne(M[(size_t)k0 * NOUT + col]);
    uint32_t hi = bf16_rne(M[(size_t)(k0 + 1) * NOUT + col]);
    Mf[t] = lo | (hi << 16);
}

// ---------------- CSR build ------------------------------------------------
__global__ __launch_bounds__(256) void hist_k(const int* __restrict__ ei,
                                              int* __restrict__ counts) {
    int e = blockIdx.x * 256 + threadIdx.x;
    if (e < NE) atomicAdd(&counts[ei[e]], 1);   // ei[e] = dst
}

__global__ __launch_bounds__(1024) void scan_k(const int* __restrict__ counts,
                                               int* __restrict__ cursor) {
    __shared__ int part[1024];
    int t = threadIdx.x;
    int base = t * 20;
    int local[20];
    int s = 0;
    #pragma unroll
    for (int k = 0; k < 20; k++) {
        int idx = base + k;
        int c = (idx < NV) ? counts[idx] : 0;
        local[k] = c; s += c;
    }
    part[t] = s;
    __syncthreads();
    for (int off = 1; off < 1024; off <<= 1) {
        int add = (t >= off) ? part[t - off] : 0;
        __syncthreads();
        part[t] += add;
        __syncthreads();
    }
    int run = (t == 0) ? 0 : part[t - 1];
    #pragma unroll
    for (int k = 0; k < 20; k++) {
        int idx = base + k;
        if (idx < NV) { cursor[idx] = run; run += local[k]; }
    }
}

__global__ __launch_bounds__(256) void scatter_k(const int* __restrict__ ei,
                                                 int* __restrict__ cursor,
                                                 int* __restrict__ order) {
    int e = blockIdx.x * 256 + threadIdx.x;
    if (e >= NE) return;
    int pos = atomicAdd(&cursor[ei[e]], 1);
    order[pos] = e;
}

// ---------------- edge prepass: CSR-ordered edge records -------------------
// SRC[k] = src vertex of k-th CSR edge; REC[k] = {c1,s1,p0..p9} (3 float4).
// Slot k = NE holds a zero record (p = 0) used to clamp the zbuild pipeline.
__global__ __launch_bounds__(256) void edge_pack(const int* __restrict__ ei,
                                                 const float* __restrict__ pre,
                                                 const float* __restrict__ conn,
                                                 const int* __restrict__ order,
                                                 int* __restrict__ SRC,
                                                 float4* __restrict__ REC) {
    int k = blockIdx.x * 256 + threadIdx.x;
    if (k > NE) return;
    if (k == NE) {
        SRC[NE] = 0;
        REC[(size_t)NE * 3 + 0] = float4{0.f, 0.f, 0.f, 0.f};
        REC[(size_t)NE * 3 + 1] = float4{0.f, 0.f, 0.f, 0.f};
        REC[(size_t)NE * 3 + 2] = float4{0.f, 0.f, 0.f, 0.f};
        return;
    }
    int e = order[k];
    SRC[k] = ei[NE + e];
    float al = conn[e];
    float c1 = __cosf(al), s1 = __sinf(al);
    const float* pp = pre + (size_t)e * 10;
    REC[(size_t)k * 3 + 0] = float4{c1, s1, pp[0], pp[1]};
    REC[(size_t)k * 3 + 1] = float4{pp[2], pp[3], pp[4], pp[5]};
    REC[(size_t)k * 3 + 2] = float4{pp[6], pp[7], pp[8], pp[9]};
}

// ---------------- Z build v2: 2 threads per (v,c), pipelined gather --------
// Thread t -> pair = t>>1 = (v-v0)*C + c, h = t&1; lane h takes edges
// beg+h, beg+h+2, ...  Partials combined via __shfl_xor(.,1).  Edge loop is
// software-pipelined: SRC prefetched a full iteration ahead, x-gather + rec
// loads for edge n+1 issued before the FMA block of edge n.  Store keeps the
// round-13 LDS-staged line-coherent writeout.
template<int C>
__global__ __launch_bounds__(256) void zbuild2(const float* __restrict__ xin,
                                               const int*   __restrict__ SRC,
                                               const float4* __restrict__ REC,
                                               const int* __restrict__ cursor,
                                               uint32_t* __restrict__ Z,
                                               int v0, int v1) {
    __shared__ uint32_t st[3200];        // 128 pairs x 25 uints = 12.8 KB
    int tid = threadIdx.x;
    int t = blockIdx.x * 256 + tid;
    int pair = t >> 1, h = t & 1;
    int rows = v1 - v0;
    int vl = pair / C;
    int c = pair % C;
    bool tvalid = vl < rows;
    int v = v0 + (tvalid ? vl : rows - 1);
    int beg = (v == 0) ? 0 : cursor[v - 1];
    int end = cursor[v];
    if (!tvalid) end = beg;

    float acc[50];
    #pragma unroll
    for (int z = 0; z < 50; z++) acc[z] = 0.f;

    int k = beg + h;
    if (k < end) {
        // prologue: current edge k fully loaded, src for k+2 prefetched
        int kn = (k + 2 < end) ? k + 2 : NE;
        int sC = SRC[k];
        int sN = SRC[kn];
        const float4* rp = REC + (size_t)k * 3;
        float4 r0 = rp[0], r1 = rp[1], r2 = rp[2];
        const float* xb = xin + ((size_t)sC * C + c) * DIN;
        float x0 = xb[0], x1 = xb[1], x2 = xb[2], x3 = xb[3], x4 = xb[4];
        while (true) {
            bool more = (k + 2 < end);
            int kn2 = (k + 4 < end) ? k + 4 : NE;
            int sN2 = SRC[kn2];
            // issue next edge's loads (sN ready since last iteration)
            const float* xbn = xin + ((size_t)sN * C + c) * DIN;
            float y0 = xbn[0], y1 = xbn[1], y2 = xbn[2], y3 = xbn[3],
                  y4 = xbn[4];
            const float4* rpn = REC + (size_t)kn * 3;
            float4 n0 = rpn[0], n1 = rpn[1], n2 = rpn[2];
            // compute current edge
            float c1 = r0.x, s1 = r0.y;
            float c2 = c1 * c1 - s1 * s1, s2 = 2.f * c1 * s1;
            float xt[5];
            xt[0] = x0;
            xt[1] = c1 * x1 - s1 * x2;
            xt[2] = s1 * x1 + c1 * x2;
            xt[3] = c2 * x3 - s2 * x4;
            xt[4] = s2 * x3 + c2 * x4;
            float p[10] = {r0.z, r0.w, r1.x, r1.y, r1.z, r1.w,
                           r2.x, r2.y, r2.z, r2.w};
            #pragma unroll
            for (int j = 0; j < 5; j++)
                #pragma unroll
                for (int q = 0; q < 10; q++)
                    acc[j * 10 + q] = fmaf(xt[j], p[q], acc[j * 10 + q]);
            if (!more) break;
            k += 2;
            r0 = n0; r1 = n1; r2 = n2;
            x0 = y0; x1 = y1; x2 = y2; x3 = y3; x4 = y4;
            sN = sN2; kn = kn2;
        }
    }
    // combine the two half-partials (pairs are adjacent lanes)
    #pragma unroll
    for (int z = 0; z < 50; z++) acc[z] += __shfl_xor(acc[z], 1);
    // both lanes hold the sum: split the bf16 pack between them
    uint32_t* sb = st + (tid >> 1) * 25;
    #pragma unroll
    for (int uu = 0; uu < 13; uu++) {
        int u = uu * 2 + h;
        if (u < 25)
            sb[u] = bf16_rne(acc[2 * u]) | (bf16_rne(acc[2 * u + 1]) << 16);
    }
    __syncthreads();
    // linear block writeout: contiguous, fully-covered cache lines
    size_t gbase = (size_t)blockIdx.x * 3200;
    int pbase = blockIdx.x * 128;
    int totp = rows * C;
    for (int i = tid; i < 3200; i += 256)
        if (pbase + i / 25 < totp) Z[gbase + i] = st[i];
}

// ---------------- MFMA GEMM: Y[v,n] = sum_k Z[v,k]*M[k,n] ------------------
// 4 waves/block, 64 rows/block, all 160 cols.  B-frags (identical for the 4
// waves) live in double-buffered LDS, filled by async DMA (global_load_lds,
// width 16): per chunk, stage chunk ck+1 into Bs[buf^1] BEFORE computing ck,
// prefetch A one chunk ahead in regs, one __syncthreads per chunk.
template<int K>
__global__ __launch_bounds__(256) void gemm_mfma(const uint32_t* __restrict__ Z,
                                                 const uint32_t* __restrict__ Mf,
                                                 float* __restrict__ Y,
                                                 int rows) {
    constexpr int NC = K / 32;
    __shared__ uint4 Bs[2][640];        // 2 x 10 KB
    int t = threadIdx.x;
    int lane = t & 63;
    int wave = t >> 6;
    int r0 = blockIdx.x * 64 + wave * 16;
    int mrow = lane & 15;
    int q = lane >> 4;
    int ra = r0 + mrow;
    if (ra >= rows) ra = rows - 1;          // clamp A loads; store masked
    const uint32_t* za = Z + (size_t)ra * (K / 2) + q * 4;
    const uint4* mfg = (const uint4*)Mf + lane;

    auto stage = [&](int ck, int nb) {
        const uint4* gp = mfg + (size_t)ck * 640;
        for (int i = wave; i < 10; i += 4)
            __builtin_amdgcn_global_load_lds(
                (const __attribute__((address_space(1))) void*)(gp + i * 64),
                (__attribute__((address_space(3))) void*)(&Bs[nb][i * 64]),
                16, 0, 0);
    };

    f32x4 acc[10];
    #pragma unroll
    for (int nt = 0; nt < 10; nt++) acc[nt] = {0.f, 0.f, 0.f, 0.f};

    stage(0, 0);
    bf16x8 af = *(const bf16x8*)za;         // A chunk 0 (overlaps DMA wait)
    __syncthreads();

    for (int ck = 0; ck < NC; ck++) {
        int buf = ck & 1;
        bf16x8 af_n = af;
        if (ck + 1 < NC) {
            stage(ck + 1, buf ^ 1);         // async DMA, consumed next iter
            af_n = *(const bf16x8*)(za + (ck + 1) * 16);
        }
        bf16x8 bf[10];
        #pragma unroll
        for (int nt = 0; nt < 10; nt++)
            bf[nt] = *(const bf16x8*)&Bs[buf][nt * 64 + lane];
        #pragma unroll
        for (int nt = 0; nt < 10; nt++)
            acc[nt] = __builtin_amdgcn_mfma_f32_16x16x32_bf16(af, bf[nt],
                                                              acc[nt], 0, 0, 0);
        af = af_n;
        __syncthreads();                    // drain DMA + protect Bs[buf]
    }
    // C/D layout: col = lane&15, row = q*4 + reg  [verified m89/m91]
    #pragma unroll
    for (int reg = 0; reg < 4; reg++) {
        int rr = r0 + q * 4 + reg;
        if (rr < rows) {
            float* yb = Y + (size_t)rr * NOUT + (lane & 15);
            #pragma unroll
            for (int nt = 0; nt < 10; nt++) yb[nt * 16] = acc[nt][reg];
        }
    }
}

// ---------------- Fourier ReLU + epilogues ---------------------------------
__device__ __forceinline__ void fourier_relu(float d0, float d1, float d2,
                                             float d3, float d4, float* out5) {
    float o0 = 0, o1 = 0, o2 = 0, o3 = 0, o4 = 0;
    #pragma unroll
    for (int k = 0; k < 7; k++) {
        float th = (float)k * (6.28318530717958647692f / 7.0f);
        float ck = __cosf(th), sk = __sinf(th);
        float c2k = ck * ck - sk * sk, s2k = 2.f * ck * sk;
        float sv = d0 + ck * d1 + sk * d2 + c2k * d3 + s2k * d4;
        sv = fmaxf(sv, 0.f);
        o0 += sv; o1 += sv * ck; o2 += sv * sk; o3 += sv * c2k; o4 += sv * s2k;
    }
    const float i7 = 1.0f / 7.0f;
    out5[0] = o0 * i7; out5[1] = o1 * (2.f * i7); out5[2] = o2 * (2.f * i7);
    out5[3] = o3 * (2.f * i7); out5[4] = o4 * (2.f * i7);
}

__global__ __launch_bounds__(256) void relu_mid(float* __restrict__ y,
                                                const float* __restrict__ b1) {
    int t = blockIdx.x * 256 + threadIdx.x;     // v*32 + ch
    if (t >= NV * 32) return;
    int ch = t & 31;
    float* yb = y + (size_t)t * 5;
    float r[5];
    fourier_relu(yb[0] + b1[ch], yb[1], yb[2], yb[3], yb[4], r);
    #pragma unroll
    for (int d = 0; d < 5; d++) yb[d] = r[d];
}

__global__ __launch_bounds__(256) void final_k(const float* __restrict__ y2,
                                               const float* __restrict__ x,
                                               const float* __restrict__ Wl,
                                               const float* __restrict__ bl,
                                               const float* __restrict__ b2,
                                               float* __restrict__ out) {
    int t = blockIdx.x * 256 + threadIdx.x;     // v*32 + o
    if (t >= NV * 32) return;
    int o = t & 31;
    int v = t >> 5;
    float r0 = 0, r1 = 0, r2 = 0, r3 = 0, r4 = 0;
    const float* xb = x + (size_t)v * (IC1 * DIN);
    const float* wl = Wl + o * IC1;
    #pragma unroll
    for (int c = 0; c < IC1; c++) {
        float w = wl[c];
        r0 = fmaf(w, xb[c*5+0], r0); r1 = fmaf(w, xb[c*5+1], r1);
        r2 = fmaf(w, xb[c*5+2], r2); r3 = fmaf(w, xb[c*5+3], r3);
        r4 = fmaf(w, xb[c*5+4], r4);
    }
    float blo = bl[o];
    const float* yb = y2 + (size_t)t * 5;
    float d0 = yb[0] + b2[o] + r0 + blo;
    float d1 = yb[1] + r1 + blo;
    float d2 = yb[2] + r2 + blo;
    float d3 = yb[3] + r3 + blo;
    float d4 = yb[4] + r4 + blo;
    float r[5];
    fourier_relu(d0, d1, d2, d3, d4, r);
    float* ob = out + (size_t)t * 5;
    #pragma unroll
    for (int d = 0; d < 5; d++) ob[d] = r[d];
}

extern "C" void kernel_launch(void* const* d_in, const int* in_sizes, int n_in,
                              void* d_out, int out_size, void* d_ws, size_t ws_size,
                              hipStream_t stream) {
    const float* x    = (const float*)d_in[0];
    const int*   ei   = (const int*)  d_in[1];
    const float* pre  = (const float*)d_in[2];
    const float* conn = (const float*)d_in[3];
    const float* W1   = (const float*)d_in[4];
    const float* b1   = (const float*)d_in[5];
    const float* W2   = (const float*)d_in[6];
    const float* b2   = (const float*)d_in[7];
    const float* Wl   = (const float*)d_in[8];
    const float* bl   = (const float*)d_in[9];
    float* out = (float*)d_out;

    const int K1 = IC1 * 50;   // 800
    const int K2 = OC  * 50;   // 1600

    // ws layout: y1 | y2 | M1 | M2 | Mf1 | Mf2 | csr | REC | SRC | Ztail
    const size_t Y_BYTES   = (size_t)NV * NOUT * sizeof(float);     // 12.8 MB
    const size_t M1_BYTES  = (size_t)K1 * NOUT * sizeof(float);     // 512 KB
    const size_t M2_BYTES  = (size_t)K2 * NOUT * sizeof(float);     // 1 MB
    const size_t MF1_BYTES = (size_t)(K1 / 32) * 10 * 64 * 16;      // 256 KB
    const size_t MF2_BYTES = (size_t)(K2 / 32) * 10 * 64 * 16;      // 512 KB
    const size_t CSR_BYTES = (size_t)(2 * NV + NE) * sizeof(int);   // 800 KB
    const size_t REC_BYTES = (size_t)(NE + 1) * 48;                 // 7.68 MB
    const size_t SRC_BYTES = (((size_t)(NE + 1) * 4 + 15) / 16) * 16;
    char* ws = (char*)d_ws;
    float* y1 = (float*)(ws);
    float* y2 = (float*)(ws + Y_BYTES);
    float* M1 = (float*)(ws + 2 * Y_BYTES);
    float* M2 = (float*)(ws + 2 * Y_BYTES + M1_BYTES);
    uint32_t* Mf1 = (uint32_t*)(ws + 2 * Y_BYTES + M1_BYTES + M2_BYTES);
    uint32_t* Mf2 = (uint32_t*)(ws + 2 * Y_BYTES + M1_BYTES + M2_BYTES + MF1_BYTES);
    int* counts = (int*)(ws + 2 * Y_BYTES + M1_BYTES + M2_BYTES + MF1_BYTES + MF2_BYTES);
    int* cursor = counts + NV;
    int* order  = cursor + NV;
    size_t csr_end = 2 * Y_BYTES + M1_BYTES + M2_BYTES + MF1_BYTES + MF2_BYTES
                   + CSR_BYTES;
    float4* REC = (float4*)(ws + csr_end);
    int*    SRC = (int*)(ws + csr_end + REC_BYTES);
    size_t fixed = csr_end + REC_BYTES + SRC_BYTES;

    // Z buffer (bf16): ws tail if it has room, else d_out (dead until final_k)
    size_t tail = (ws_size > fixed) ? (ws_size - fixed) : 0;
    uint32_t* zbuf;
    size_t zcap;
    if (tail >= Y_BYTES) { zbuf = (uint32_t*)(ws + fixed); zcap = tail; }
    else                 { zbuf = (uint32_t*)d_out;        zcap = Y_BYTES; }
    int chunk1 = (int)(zcap / ((size_t)K1 * 2)); if (chunk1 > NV) chunk1 = NV;
    int chunk2 = (int)(zcap / ((size_t)K2 * 2)); if (chunk2 > NV) chunk2 = NV;

    hipMemsetAsync(counts, 0, NV * sizeof(int), stream);

    build_M<IC1><<<(K1 * NOUT + 255) / 256, 256, 0, stream>>>(W1, M1);
    build_M<OC> <<<(K2 * NOUT + 255) / 256, 256, 0, stream>>>(W2, M2);
    build_Mfrag<K1><<<((K1 / 32) * 2560 + 255) / 256, 256, 0, stream>>>(M1, Mf1);
    build_Mfrag<K2><<<((K2 / 32) * 2560 + 255) / 256, 256, 0, stream>>>(M2, Mf2);

    hist_k   <<<(NE + 255) / 256, 256, 0, stream>>>(ei, counts);
    scan_k   <<<1, 1024, 0, stream>>>(counts, cursor);
    scatter_k<<<(NE + 255) / 256, 256, 0, stream>>>(ei, cursor, order);
    edge_pack<<<(NE + 256) / 256, 256, 0, stream>>>(ei, pre, conn, order,
                                                    SRC, REC);

    // layer 1
    for (int v0 = 0; v0 < NV; v0 += chunk1) {
        int v1 = v0 + chunk1; if (v1 > NV) v1 = NV;
        int rows = v1 - v0;
        zbuild2<IC1><<<((size_t)rows * IC1 * 2 + 255) / 256, 256, 0, stream>>>(
            x, SRC, REC, cursor, zbuf, v0, v1);
        gemm_mfma<K1><<<(rows + 63) / 64, 256, 0, stream>>>(
            zbuf, Mf1, y1 + (size_t)v0 * NOUT, rows);
    }
    relu_mid<<<(NV * 32 + 255) / 256, 256, 0, stream>>>(y1, b1);
    // layer 2
    for (int v0 = 0; v0 < NV; v0 += chunk2) {
        int v1 = v0 + chunk2; if (v1 > NV) v1 = NV;
        int rows = v1 - v0;
        zbuild2<OC><<<((size_t)rows * OC * 2 + 255) / 256, 256, 0, stream>>>(
            y1, SRC, REC, cursor, zbuf, v0, v1);
        gemm_mfma<K2><<<(rows + 63) / 64, 256, 0, stream>>>(
            zbuf, Mf2, y2 + (size_t)v0 * NOUT, rows);
    }
    final_k<<<(NV * 32 + 255) / 256, 256, 0, stream>>>(y2, x, Wl, bl, b2, out);
}

// Round 2
// 278.197 us; speedup vs baseline: 1.3785x; 1.3785x over previous
//
#include <hip/hip_runtime.h>
#include <hip/hip_bf16.h>
#include <cstdint>

// ---------------------------------------------------------------------------
// GemResNetBlock: two gauge-equivariant convs + Fourier ReLU + linear residual
// Round-15: round-14's 2-way split regressed (WRITE_SIZE 62.5->530 MB) because
// the bf16 pack loop runtime-indexed acc[] (acc[2*(uu*2+h)], h=tid&1) -> the
// whole acc[50] array was demoted to scratch (rule #20), turning every FMA
// into scratch R/W traffic.  This round keeps the useful parts:
//  * edge_pack prepass: CSR-ordered SRC[] + 48B rec {c1,s1,p[10]} (one sincos
//    per edge total, shared by both layers; kills 2 gather-chain levels)
//  * software-pipelined edge loop (SRC 1 iter ahead; x/REC for edge n+1
//    issued before the FMA block of edge n), zero-record clamp at k=NE
// and reverts to round-13's scratch-free structure: 1 thread per (v,c),
// every acc[] index compile-time constant, LDS-staged line-coherent store.
#define NV     20000
#define NE     160000
#define IC1    16
#define OC     32
#define DIN    5
#define NSLOT  49
#define NOUT   160              // (o,i) = 32*5
// ---------------------------------------------------------------------------
struct SlotTables {
    int n;
    int b[64], f[64], i[64], j[64];
    float v[64];
};

constexpr SlotTables make_slots() {
    SlotTables T{};
    float K[19][5][5][5] = {};   // [basis][freq][row i][col j]
    int nb = 0;
    const int BL = 2;
    auto add = [&](int f, const float (*cb)[2], const float (*sb)[2],
                   int m, int n) {
        if (f > BL) return;
        int r0 = (m == 0) ? 0 : (2 * m - 1), nr = (m == 0) ? 1 : 2;
        int c0 = (n == 0) ? 0 : (2 * n - 1), nc = (n == 0) ? 1 : 2;
        for (int a = 0; a < nr; a++)
            for (int bb = 0; bb < nc; bb++) {
                if (f == 0) {
                    K[nb][0][r0 + a][c0 + bb] = cb[a][bb];
                } else {
                    K[nb][2 * f - 1][r0 + a][c0 + bb] = cb[a][bb];
                    K[nb][2 * f    ][r0 + a][c0 + bb] = sb[a][bb];
                }
            }
        nb++;
    };
    const float ONE[2][2]  = {{1, 0}, {0, 0}};
    const float I2[2][2]   = {{1, 0}, {0, 1}};
    const float E2[2][2]   = {{0, -1}, {1, 0}};
    const float S2[2][2]   = {{1, 0}, {0, -1}};
    const float ES2[2][2]  = {{0, 1}, {1, 0}};
    const float NS2[2][2]  = {{-1, 0}, {0, 1}};
    const float C10[2][2]  = {{1, 0}, {0, 0}};
    const float C01[2][2]  = {{0, 0}, {1, 0}};
    const float CM10[2][2] = {{-1, 0}, {0, 0}};
    const float R10[2][2]  = {{1, 0}, {0, 0}};
    const float R01[2][2]  = {{0, 1}, {0, 0}};
    const float RM10[2][2] = {{-1, 0}, {0, 0}};

    for (int m = 0; m <= 2; m++)
        for (int n = 0; n <= 2; n++) {
            if (m == 0 && n == 0) {
                add(0, ONE, ONE, 0, 0);
            } else if (n == 0) {
                add(m, C10, C01, m, 0);
                add(m, C01, CM10, m, 0);
            } else if (m == 0) {
                add(n, R10, R01, 0, n);
                add(n, R01, RM10, 0, n);
            } else {
                int d = m - n;
                int f = d >= 0 ? d : -d;
                float sg = d >= 0 ? 1.f : -1.f;
                const float sgE[2][2]  = {{0, -sg}, {sg, 0}};
                const float msgI[2][2] = {{-sg, 0}, {0, -sg}};
                add(f, I2, sgE, m, n);
                add(f, E2, msgI, m, n);
                add(m + n, S2, ES2, m, n);
                add(m + n, ES2, NS2, m, n);
            }
        }
    T.n = 0;
    for (int i = 0; i < 5; i++)
        for (int b = 0; b < nb; b++)
            for (int f = 0; f < 5; f++)
                for (int j = 0; j < 5; j++)
                    if (K[b][f][i][j] != 0.0f) {
                        T.b[T.n] = b; T.f[T.n] = f; T.i[T.n] = i;
                        T.j[T.n] = j; T.v[T.n] = K[b][f][i][j];
                        T.n++;
                    }
    return T;
}

constexpr SlotTables SL = make_slots();
static_assert(SL.n == NSLOT, "expect 49 kernel-basis nonzeros");

__device__ __forceinline__ uint32_t bf16_rne(float f) {
    uint32_t u = __float_as_uint(f);
    u += 0x7fffu + ((u >> 16) & 1u);
    return u >> 16;
}

typedef __attribute__((ext_vector_type(8))) short bf16x8;   // MFMA A/B frag
typedef __attribute__((ext_vector_type(4))) float f32x4;    // MFMA C/D frag

// ---------------- M build: M[k][n], k=(c*50+j*10+q), n=(o*5+i) -------------
template<int C>
__global__ __launch_bounds__(256) void build_M(const float* __restrict__ W,
                                               float* __restrict__ M) {
    int t = blockIdx.x * 256 + threadIdx.x;
    const int K = C * 50;
    if (t >= K * NOUT) return;
    int n = t % NOUT, k = t / NOUT;
    int o = n / 5, i = n % 5;
    int c = k / 50, r50 = k % 50;
    int j = r50 / 10, q = r50 % 10;
    int f = q >> 1, r = q & 1;
    float acc = 0.f;
    #pragma unroll
    for (int s = 0; s < NSLOT; s++) {
        if (SL.j[s] == j && SL.f[s] == f && SL.i[s] == i)
            acc += SL.v[s] * W[(size_t)((SL.b[s] * 2 + r) * 32 + o) * C + c];
    }
    M[(size_t)k * NOUT + n] = acc;
}

// Swizzle M into MFMA B-fragment order (bf16):
// Mf[((ck*10+nt)*64+lane)*4+a] packs B[k0][col],B[k0+1][col]
// with k0 = ck*32 + (lane>>4)*8 + 2a, col = nt*16 + (lane&15).
template<int K>
__global__ __launch_bounds__(256) void build_Mfrag(const float* __restrict__ M,
                                                   uint32_t* __restrict__ Mf) {
    int t = blockIdx.x * 256 + threadIdx.x;
    const int total = (K / 32) * 10 * 64 * 4;
    if (t >= total) return;
    int a = t & 3;
    int idx = t >> 2;
    int lane = idx & 63; idx >>= 6;
    int nt = idx % 10;
    int ck = idx / 10;
    int col = nt * 16 + (lane & 15);
    int k0 = ck * 32 + (lane >> 4) * 8 + 2 * a;
    uint32_t lo = bf16_rne(M[(size_t)k0 * NOUT + col]);
    uint32_t hi = bf16_rne(M[(size_t)(k0 + 1) * NOUT + col]);
    Mf[t] = lo | (hi << 16);
}

// ---------------- CSR build ------------------------------------------------
__global__ __launch_bounds__(256) void hist_k(const int* __restrict__ ei,
                                              int* __restrict__ counts) {
    int e = blockIdx.x * 256 + threadIdx.x;
    if (e < NE) atomicAdd(&counts[ei[e]], 1);   // ei[e] = dst
}

__global__ __launch_bounds__(1024) void scan_k(const int* __restrict__ counts,
                                               int* __restrict__ cursor) {
    __shared__ int part[1024];
    int t = threadIdx.x;
    int base = t * 20;
    int local[20];
    int s = 0;
    #pragma unroll
    for (int k = 0; k < 20; k++) {
        int idx = base + k;
        int c = (idx < NV) ? counts[idx] : 0;
        local[k] = c; s += c;
    }
    part[t] = s;
    __syncthreads();
    for (int off = 1; off < 1024; off <<= 1) {
        int add = (t >= off) ? part[t - off] : 0;
        __syncthreads();
        part[t] += add;
        __syncthreads();
    }
    int run = (t == 0) ? 0 : part[t - 1];
    #pragma unroll
    for (int k = 0; k < 20; k++) {
        int idx = base + k;
        if (idx < NV) { cursor[idx] = run; run += local[k]; }
    }
}

__global__ __launch_bounds__(256) void scatter_k(const int* __restrict__ ei,
                                                 int* __restrict__ cursor,
                                                 int* __restrict__ order) {
    int e = blockIdx.x * 256 + threadIdx.x;
    if (e >= NE) return;
    int pos = atomicAdd(&cursor[ei[e]], 1);
    order[pos] = e;
}

// ---------------- edge prepass: CSR-ordered edge records -------------------
// SRC[k] = src vertex of k-th CSR edge; REC[k] = {c1,s1,p0..p9} (3 float4).
// Slot k = NE holds a zero record (p = 0) used to clamp the zbuild pipeline.
__global__ __launch_bounds__(256) void edge_pack(const int* __restrict__ ei,
                                                 const float* __restrict__ pre,
                                                 const float* __restrict__ conn,
                                                 const int* __restrict__ order,
                                                 int* __restrict__ SRC,
                                                 float4* __restrict__ REC) {
    int k = blockIdx.x * 256 + threadIdx.x;
    if (k > NE) return;
    if (k == NE) {
        SRC[NE] = 0;
        REC[(size_t)NE * 3 + 0] = float4{0.f, 0.f, 0.f, 0.f};
        REC[(size_t)NE * 3 + 1] = float4{0.f, 0.f, 0.f, 0.f};
        REC[(size_t)NE * 3 + 2] = float4{0.f, 0.f, 0.f, 0.f};
        return;
    }
    int e = order[k];
    SRC[k] = ei[NE + e];
    float al = conn[e];
    float c1 = __cosf(al), s1 = __sinf(al);
    const float* pp = pre + (size_t)e * 10;
    REC[(size_t)k * 3 + 0] = float4{c1, s1, pp[0], pp[1]};
    REC[(size_t)k * 3 + 1] = float4{pp[2], pp[3], pp[4], pp[5]};
    REC[(size_t)k * 3 + 2] = float4{pp[6], pp[7], pp[8], pp[9]};
}

// ---------------- Z build v3: 1 thread per (v,c), pipelined gather ---------
// Edge loop is software-pipelined: SRC prefetched a full iteration ahead,
// x-gather + REC loads for edge n+1 issued before the FMA block of edge n.
// All acc[] indices are compile-time constants (no scratch).  Store goes
// through the round-13 LDS-staged transpose so every global store covers
// fully-written contiguous cache lines.
template<int C>
__global__ __launch_bounds__(256) void zbuild3(const float* __restrict__ xin,
                                               const int*   __restrict__ SRC,
                                               const float4* __restrict__ REC,
                                               const int* __restrict__ cursor,
                                               uint32_t* __restrict__ Z,
                                               int v0, int v1) {
    __shared__ uint32_t st[6400];        // 256 rows x 25 uints = 25.6 KB
    int tid = threadIdx.x;
    int t = blockIdx.x * 256 + tid;
    int rows = (v1 - v0) * C;
    bool valid = (t < rows);
    int c = t % C;
    int v = v0 + t / C;
    int beg = 0, end = 0;
    if (valid) { beg = (v == 0) ? 0 : cursor[v - 1]; end = cursor[v]; }

    float acc[50];
    #pragma unroll
    for (int z = 0; z < 50; z++) acc[z] = 0.f;

    int k = beg;
    if (k < end) {
        // prologue: edge k fully loaded, src of k+1 prefetched
        int kn = (k + 1 < end) ? k + 1 : NE;
        int sC = SRC[k];
        int sN = SRC[kn];
        const float4* rp = REC + (size_t)k * 3;
        float4 r0 = rp[0], r1 = rp[1], r2 = rp[2];
        const float* xb = xin + ((size_t)sC * C + c) * DIN;
        float x0 = xb[0], x1 = xb[1], x2 = xb[2], x3 = xb[3], x4 = xb[4];
        while (true) {
            bool more = (k + 1 < end);
            int kn2 = (k + 2 < end) ? k + 2 : NE;
            int sN2 = SRC[kn2];
            // issue next edge's loads (sN ready since last iteration)
            const float* xbn = xin + ((size_t)sN * C + c) * DIN;
            float y0 = xbn[0], y1 = xbn[1], y2 = xbn[2], y3 = xbn[3],
                  y4 = xbn[4];
            const float4* rpn = REC + (size_t)kn * 3;
            float4 n0 = rpn[0], n1 = rpn[1], n2 = rpn[2];
            // compute current edge
            float c1 = r0.x, s1 = r0.y;
            float c2 = c1 * c1 - s1 * s1, s2 = 2.f * c1 * s1;
            float xt[5];
            xt[0] = x0;
            xt[1] = c1 * x1 - s1 * x2;
            xt[2] = s1 * x1 + c1 * x2;
            xt[3] = c2 * x3 - s2 * x4;
            xt[4] = s2 * x3 + c2 * x4;
            float p[10] = {r0.z, r0.w, r1.x, r1.y, r1.z, r1.w,
                           r2.x, r2.y, r2.z, r2.w};
            #pragma unroll
            for (int j = 0; j < 5; j++)
                #pragma unroll
                for (int q = 0; q < 10; q++)
                    acc[j * 10 + q] = fmaf(xt[j], p[q], acc[j * 10 + q]);
            if (!more) break;
            k += 1;
            r0 = n0; r1 = n1; r2 = n2;
            x0 = y0; x1 = y1; x2 = y2; x3 = y3; x4 = y4;
            sN = sN2; kn = kn2;
        }
    }
    // stage 25 packed uints into LDS (stride 25: odd -> 2-way alias, free);
    // all indices compile-time constant -> acc stays in registers
    uint32_t* sb = st + tid * 25;
    #pragma unroll
    for (int z = 0; z < 25; z++)
        sb[z] = bf16_rne(acc[2 * z]) | (bf16_rne(acc[2 * z + 1]) << 16);
    __syncthreads();
    // linear block writeout: each store inst covers contiguous cache lines
    size_t gbase = (size_t)blockIdx.x * 6400;
    int rbase = blockIdx.x * 256;
    for (int i = tid; i < 6400; i += 256) {
        if (rbase + i / 25 < rows) Z[gbase + i] = st[i];
    }
}

// ---------------- MFMA GEMM: Y[v,n] = sum_k Z[v,k]*M[k,n] ------------------
// 4 waves/block, 64 rows/block, all 160 cols.  B-frags (identical for the 4
// waves) live in double-buffered LDS, filled by async DMA (global_load_lds,
// width 16): per chunk, stage chunk ck+1 into Bs[buf^1] BEFORE computing ck,
// prefetch A one chunk ahead in regs, one __syncthreads per chunk.
template<int K>
__global__ __launch_bounds__(256) void gemm_mfma(const uint32_t* __restrict__ Z,
                                                 const uint32_t* __restrict__ Mf,
                                                 float* __restrict__ Y,
                                                 int rows) {
    constexpr int NC = K / 32;
    __shared__ uint4 Bs[2][640];        // 2 x 10 KB
    int t = threadIdx.x;
    int lane = t & 63;
    int wave = t >> 6;
    int r0 = blockIdx.x * 64 + wave * 16;
    int mrow = lane & 15;
    int q = lane >> 4;
    int ra = r0 + mrow;
    if (ra >= rows) ra = rows - 1;          // clamp A loads; store masked
    const uint32_t* za = Z + (size_t)ra * (K / 2) + q * 4;
    const uint4* mfg = (const uint4*)Mf + lane;

    auto stage = [&](int ck, int nb) {
        const uint4* gp = mfg + (size_t)ck * 640;
        for (int i = wave; i < 10; i += 4)
            __builtin_amdgcn_global_load_lds(
                (const __attribute__((address_space(1))) void*)(gp + i * 64),
                (__attribute__((address_space(3))) void*)(&Bs[nb][i * 64]),
                16, 0, 0);
    };

    f32x4 acc[10];
    #pragma unroll
    for (int nt = 0; nt < 10; nt++) acc[nt] = {0.f, 0.f, 0.f, 0.f};

    stage(0, 0);
    bf16x8 af = *(const bf16x8*)za;         // A chunk 0 (overlaps DMA wait)
    __syncthreads();

    for (int ck = 0; ck < NC; ck++) {
        int buf = ck & 1;
        bf16x8 af_n = af;
        if (ck + 1 < NC) {
            stage(ck + 1, buf ^ 1);         // async DMA, consumed next iter
            af_n = *(const bf16x8*)(za + (ck + 1) * 16);
        }
        bf16x8 bf[10];
        #pragma unroll
        for (int nt = 0; nt < 10; nt++)
            bf[nt] = *(const bf16x8*)&Bs[buf][nt * 64 + lane];
        #pragma unroll
        for (int nt = 0; nt < 10; nt++)
            acc[nt] = __builtin_amdgcn_mfma_f32_16x16x32_bf16(af, bf[nt],
                                                              acc[nt], 0, 0, 0);
        af = af_n;
        __syncthreads();                    // drain DMA + protect Bs[buf]
    }
    // C/D layout: col = lane&15, row = q*4 + reg  [verified m89/m91]
    #pragma unroll
    for (int reg = 0; reg < 4; reg++) {
        int rr = r0 + q * 4 + reg;
        if (rr < rows) {
            float* yb = Y + (size_t)rr * NOUT + (lane & 15);
            #pragma unroll
            for (int nt = 0; nt < 10; nt++) yb[nt * 16] = acc[nt][reg];
        }
    }
}

// ---------------- Fourier ReLU + epilogues ---------------------------------
__device__ __forceinline__ void fourier_relu(float d0, float d1, float d2,
                                             float d3, float d4, float* out5) {
    float o0 = 0, o1 = 0, o2 = 0, o3 = 0, o4 = 0;
    #pragma unroll
    for (int k = 0; k < 7; k++) {
        float th = (float)k * (6.28318530717958647692f / 7.0f);
        float ck = __cosf(th), sk = __sinf(th);
        float c2k = ck * ck - sk * sk, s2k = 2.f * ck * sk;
        float sv = d0 + ck * d1 + sk * d2 + c2k * d3 + s2k * d4;
        sv = fmaxf(sv, 0.f);
        o0 += sv; o1 += sv * ck; o2 += sv * sk; o3 += sv * c2k; o4 += sv * s2k;
    }
    const float i7 = 1.0f / 7.0f;
    out5[0] = o0 * i7; out5[1] = o1 * (2.f * i7); out5[2] = o2 * (2.f * i7);
    out5[3] = o3 * (2.f * i7); out5[4] = o4 * (2.f * i7);
}

__global__ __launch_bounds__(256) void relu_mid(float* __restrict__ y,
                                                const float* __restrict__ b1) {
    int t = blockIdx.x * 256 + threadIdx.x;     // v*32 + ch
    if (t >= NV * 32) return;
    int ch = t & 31;
    float* yb = y + (size_t)t * 5;
    float r[5];
    fourier_relu(yb[0] + b1[ch], yb[1], yb[2], yb[3], yb[4], r);
    #pragma unroll
    for (int d = 0; d < 5; d++) yb[d] = r[d];
}

__global__ __launch_bounds__(256) void final_k(const float* __restrict__ y2,
                                               const float* __restrict__ x,
                                               const float* __restrict__ Wl,
                                               const float* __restrict__ bl,
                                               const float* __restrict__ b2,
                                               float* __restrict__ out) {
    int t = blockIdx.x * 256 + threadIdx.x;     // v*32 + o
    if (t >= NV * 32) return;
    int o = t & 31;
    int v = t >> 5;
    float r0 = 0, r1 = 0, r2 = 0, r3 = 0, r4 = 0;
    const float* xb = x + (size_t)v * (IC1 * DIN);
    const float* wl = Wl + o * IC1;
    #pragma unroll
    for (int c = 0; c < IC1; c++) {
        float w = wl[c];
        r0 = fmaf(w, xb[c*5+0], r0); r1 = fmaf(w, xb[c*5+1], r1);
        r2 = fmaf(w, xb[c*5+2], r2); r3 = fmaf(w, xb[c*5+3], r3);
        r4 = fmaf(w, xb[c*5+4], r4);
    }
    float blo = bl[o];
    const float* yb = y2 + (size_t)t * 5;
    float d0 = yb[0] + b2[o] + r0 + blo;
    float d1 = yb[1] + r1 + blo;
    float d2 = yb[2] + r2 + blo;
    float d3 = yb[3] + r3 + blo;
    float d4 = yb[4] + r4 + blo;
    float r[5];
    fourier_relu(d0, d1, d2, d3, d4, r);
    float* ob = out + (size_t)t * 5;
    #pragma unroll
    for (int d = 0; d < 5; d++) ob[d] = r[d];
}

extern "C" void kernel_launch(void* const* d_in, const int* in_sizes, int n_in,
                              void* d_out, int out_size, void* d_ws, size_t ws_size,
                              hipStream_t stream) {
    const float* x    = (const float*)d_in[0];
    const int*   ei   = (const int*)  d_in[1];
    const float* pre  = (const float*)d_in[2];
    const float* conn = (const float*)d_in[3];
    const float* W1   = (const float*)d_in[4];
    const float* b1   = (const float*)d_in[5];
    const float* W2   = (const float*)d_in[6];
    const float* b2   = (const float*)d_in[7];
    const float* Wl   = (const float*)d_in[8];
    const float* bl   = (const float*)d_in[9];
    float* out = (float*)d_out;

    const int K1 = IC1 * 50;   // 800
    const int K2 = OC  * 50;   // 1600

    // ws layout: y1 | y2 | M1 | M2 | Mf1 | Mf2 | csr | REC | SRC | Ztail
    const size_t Y_BYTES   = (size_t)NV * NOUT * sizeof(float);     // 12.8 MB
    const size_t M1_BYTES  = (size_t)K1 * NOUT * sizeof(float);     // 512 KB
    const size_t M2_BYTES  = (size_t)K2 * NOUT * sizeof(float);     // 1 MB
    const size_t MF1_BYTES = (size_t)(K1 / 32) * 10 * 64 * 16;      // 256 KB
    const size_t MF2_BYTES = (size_t)(K2 / 32) * 10 * 64 * 16;      // 512 KB
    const size_t CSR_BYTES = (size_t)(2 * NV + NE) * sizeof(int);   // 800 KB
    const size_t REC_BYTES = (size_t)(NE + 1) * 48;                 // 7.68 MB
    const size_t SRC_BYTES = (((size_t)(NE + 1) * 4 + 15) / 16) * 16;
    char* ws = (char*)d_ws;
    float* y1 = (float*)(ws);
    float* y2 = (float*)(ws + Y_BYTES);
    float* M1 = (float*)(ws + 2 * Y_BYTES);
    float* M2 = (float*)(ws + 2 * Y_BYTES + M1_BYTES);
    uint32_t* Mf1 = (uint32_t*)(ws + 2 * Y_BYTES + M1_BYTES + M2_BYTES);
    uint32_t* Mf2 = (uint32_t*)(ws + 2 * Y_BYTES + M1_BYTES + M2_BYTES + MF1_BYTES);
    int* counts = (int*)(ws + 2 * Y_BYTES + M1_BYTES + M2_BYTES + MF1_BYTES + MF2_BYTES);
    int* cursor = counts + NV;
    int* order  = cursor + NV;
    size_t csr_end = 2 * Y_BYTES + M1_BYTES + M2_BYTES + MF1_BYTES + MF2_BYTES
                   + CSR_BYTES;
    float4* REC = (float4*)(ws + csr_end);
    int*    SRC = (int*)(ws + csr_end + REC_BYTES);
    size_t fixed = csr_end + REC_BYTES + SRC_BYTES;

    // Z buffer (bf16): ws tail if it has room, else d_out (dead until final_k)
    size_t tail = (ws_size > fixed) ? (ws_size - fixed) : 0;
    uint32_t* zbuf;
    size_t zcap;
    if (tail >= Y_BYTES) { zbuf = (uint32_t*)(ws + fixed); zcap = tail; }
    else                 { zbuf = (uint32_t*)d_out;        zcap = Y_BYTES; }
    int chunk1 = (int)(zcap / ((size_t)K1 * 2)); if (chunk1 > NV) chunk1 = NV;
    int chunk2 = (int)(zcap / ((size_t)K2 * 2)); if (chunk2 > NV) chunk2 = NV;

    hipMemsetAsync(counts, 0, NV * sizeof(int), stream);

    build_M<IC1><<<(K1 * NOUT + 255) / 256, 256, 0, stream>>>(W1, M1);
    build_M<OC> <<<(K2 * NOUT + 255) / 256, 256, 0, stream>>>(W2, M2);
    build_Mfrag<K1><<<((K1 / 32) * 2560 + 255) / 256, 256, 0, stream>>>(M1, Mf1);
    build_Mfrag<K2><<<((K2 / 32) * 2560 + 255) / 256, 256, 0, stream>>>(M2, Mf2);

    hist_k   <<<(NE + 255) / 256, 256, 0, stream>>>(ei, counts);
    scan_k   <<<1, 1024, 0, stream>>>(counts, cursor);
    scatter_k<<<(NE + 255) / 256, 256, 0, stream>>>(ei, cursor, order);
    edge_pack<<<(NE + 256) / 256, 256, 0, stream>>>(ei, pre, conn, order,
                                                    SRC, REC);

    // layer 1
    for (int v0 = 0; v0 < NV; v0 += chunk1) {
        int v1 = v0 + chunk1; if (v1 > NV) v1 = NV;
        int rows = v1 - v0;
        zbuild3<IC1><<<(rows * IC1 + 255) / 256, 256, 0, stream>>>(
            x, SRC, REC, cursor, zbuf, v0, v1);
        gemm_mfma<K1><<<(rows + 63) / 64, 256, 0, stream>>>(
            zbuf, Mf1, y1 + (size_t)v0 * NOUT, rows);
    }
    relu_mid<<<(NV * 32 + 255) / 256, 256, 0, stream>>>(y1, b1);
    // layer 2
    for (int v0 = 0; v0 < NV; v0 += chunk2) {
        int v1 = v0 + chunk2; if (v1 > NV) v1 = NV;
        int rows = v1 - v0;
        zbuild3<OC><<<(rows * OC + 255) / 256, 256, 0, stream>>>(
            y1, SRC, REC, cursor, zbuf, v0, v1);
        gemm_mfma<K2><<<(rows + 63) / 64, 256, 0, stream>>>(
            zbuf, Mf2, y2 + (size_t)v0 * NOUT, rows);
    }
    final_k<<<(NV * 32 + 255) / 256, 256, 0, stream>>>(y2, x, Wl, bl, b2, out);
}